// Round 3
// baseline (228.740 us; speedup 1.0000x reference)
//
#include <hip/hip_runtime.h>
#include <hip/hip_bf16.h>
#include <math.h>

#define D_PET 128
#define NK    256
#define NB    2048
#define NBATCH 16

__device__ __forceinline__ float silu(float x) {
    return x / (1.0f + expf(-x));
}

__device__ __forceinline__ int lower_bound_dev(const int* a, int n, int v) {
    int lo = 0, hi = n;
    while (lo < hi) {
        int m = (lo + hi) >> 1;
        if (a[m] < v) lo = m + 1; else hi = m;
    }
    return lo;
}

// ---------------------------------------------------------------------------
// Kernel 1: filt[b,k,:] = MLP(kv[b,k,:])
// 8 k-vectors per block, 256 threads: d = tid&127, jg = tid>>7 -> 4 j's each.
// ---------------------------------------------------------------------------
#define MJ 8   // k-vectors per block
__global__ void mlp_kernel(const float* __restrict__ kvec,
                           const float* __restrict__ W1, const float* __restrict__ b1,
                           const float* __restrict__ W2, const float* __restrict__ b2,
                           const float* __restrict__ W3, const float* __restrict__ b3,
                           float* __restrict__ filt) {
    int bk0 = blockIdx.x * MJ;
    int d   = threadIdx.x & (D_PET - 1);
    int jg  = threadIdx.x >> 7;

    __shared__ float kv_s[MJ * 3];
    __shared__ float x_lds[D_PET * MJ];

    if (threadIdx.x < MJ * 3) kv_s[threadIdx.x] = kvec[bk0 * 3 + threadIdx.x];
    __syncthreads();

    float w10 = W1[0 * D_PET + d], w11 = W1[1 * D_PET + d], w12 = W1[2 * D_PET + d];
    float bb1 = b1[d];
    float4 x1;
    {
        float* xp = (float*)&x1;
#pragma unroll
        for (int i = 0; i < 4; i++) {
            int j = jg * 4 + i;
            float a = bb1;
            a = fmaf(kv_s[j * 3 + 0], w10, a);
            a = fmaf(kv_s[j * 3 + 1], w11, a);
            a = fmaf(kv_s[j * 3 + 2], w12, a);
            xp[i] = silu(a);
        }
    }
    *(float4*)&x_lds[(d << 3) + (jg << 2)] = x1;
    __syncthreads();

    float acc0 = b2[d], acc1 = acc0, acc2 = acc0, acc3 = acc0;
#pragma unroll 8
    for (int e = 0; e < D_PET; e++) {
        float w = W2[e * D_PET + d];
        float4 xv = *(const float4*)&x_lds[(e << 3) + (jg << 2)];
        acc0 = fmaf(xv.x, w, acc0);
        acc1 = fmaf(xv.y, w, acc1);
        acc2 = fmaf(xv.z, w, acc2);
        acc3 = fmaf(xv.w, w, acc3);
    }
    float4 x2 = make_float4(silu(acc0), silu(acc1), silu(acc2), silu(acc3));
    __syncthreads();
    *(float4*)&x_lds[(d << 3) + (jg << 2)] = x2;
    __syncthreads();

    float o0 = b3[d], o1 = o0, o2 = o0, o3 = o0;
#pragma unroll 8
    for (int e = 0; e < D_PET; e++) {
        float w = W3[e * D_PET + d];
        float4 xv = *(const float4*)&x_lds[(e << 3) + (jg << 2)];
        o0 = fmaf(xv.x, w, o0);
        o1 = fmaf(xv.y, w, o1);
        o2 = fmaf(xv.z, w, o2);
        o3 = fmaf(xv.w, w, o3);
    }
    float out4[4] = {o0, o1, o2, o3};
#pragma unroll
    for (int i = 0; i < 4; i++) {
        int j = jg * 4 + i;
        filt[(size_t)(bk0 + j) * D_PET + d] = out4[i];
    }
}

// ---------------------------------------------------------------------------
// Kernel 2: cos/sin tables [n][k].  grid = NB blocks, NK threads
// ---------------------------------------------------------------------------
__global__ void phase_kernel(const float* __restrict__ kvec,
                             const float* __restrict__ pos,
                             const int* __restrict__ batch,
                             float* __restrict__ cos_t, float* __restrict__ sin_t) {
    int n = blockIdx.x;
    int k = threadIdx.x;
    int b = batch[n];
    float p0 = pos[n * 3 + 0], p1 = pos[n * 3 + 1], p2 = pos[n * 3 + 2];
    const float* kv = kvec + ((size_t)b * NK + k) * 3;
    float ph = p0 * kv[0] + p1 * kv[1] + p2 * kv[2];
    float s, c;
    sincosf(ph, &s, &c);
    cos_t[n * NK + k] = c;
    sin_t[n * NK + k] = s;
}

// ---------------------------------------------------------------------------
// Kernel 3: t[b,k,d] = (sum_{n in b} e^{-i phi_nk} h[n,d]) * filt[b,k,d]
// grid = 16*32 = 512 blocks, 256 threads. cos/sin loads are wave-uniform
// float4 broadcasts; h loads coalesced. 8 independent FMA chains/thread.
// ---------------------------------------------------------------------------
#define SKT 8   // k per block
__global__ void s_kernel(const float* __restrict__ h,
                         const float* __restrict__ cos_t,
                         const float* __restrict__ sin_t,
                         const int* __restrict__ batch,
                         const float* __restrict__ filt,
                         float* __restrict__ t_re, float* __restrict__ t_im) {
    const int tiles = NK / SKT;                 // 32
    int b  = blockIdx.x / tiles;
    int kt = blockIdx.x % tiles;
    int d  = threadIdx.x & (D_PET - 1);
    int kg = threadIdx.x >> 7;                  // 0/1
    int k0 = kt * SKT + kg * 4;

    int lo = lower_bound_dev(batch, NB, b);
    int hi = lower_bound_dev(batch, NB, b + 1);

    float sre0 = 0.f, sre1 = 0.f, sre2 = 0.f, sre3 = 0.f;
    float sim0 = 0.f, sim1 = 0.f, sim2 = 0.f, sim3 = 0.f;

    int n = lo;
    for (; n + 1 < hi; n += 2) {
        float hv0 = h[(size_t)n * D_PET + d];
        float hv1 = h[(size_t)(n + 1) * D_PET + d];
        float4 c0 = *(const float4*)&cos_t[(size_t)n * NK + k0];
        float4 s0 = *(const float4*)&sin_t[(size_t)n * NK + k0];
        float4 c1 = *(const float4*)&cos_t[(size_t)(n + 1) * NK + k0];
        float4 s1 = *(const float4*)&sin_t[(size_t)(n + 1) * NK + k0];
        sre0 = fmaf(c0.x, hv0, sre0); sim0 = fmaf(-s0.x, hv0, sim0);
        sre1 = fmaf(c0.y, hv0, sre1); sim1 = fmaf(-s0.y, hv0, sim1);
        sre2 = fmaf(c0.z, hv0, sre2); sim2 = fmaf(-s0.z, hv0, sim2);
        sre3 = fmaf(c0.w, hv0, sre3); sim3 = fmaf(-s0.w, hv0, sim3);
        sre0 = fmaf(c1.x, hv1, sre0); sim0 = fmaf(-s1.x, hv1, sim0);
        sre1 = fmaf(c1.y, hv1, sre1); sim1 = fmaf(-s1.y, hv1, sim1);
        sre2 = fmaf(c1.z, hv1, sre2); sim2 = fmaf(-s1.z, hv1, sim2);
        sre3 = fmaf(c1.w, hv1, sre3); sim3 = fmaf(-s1.w, hv1, sim3);
    }
    if (n < hi) {
        float hv0 = h[(size_t)n * D_PET + d];
        float4 c0 = *(const float4*)&cos_t[(size_t)n * NK + k0];
        float4 s0 = *(const float4*)&sin_t[(size_t)n * NK + k0];
        sre0 = fmaf(c0.x, hv0, sre0); sim0 = fmaf(-s0.x, hv0, sim0);
        sre1 = fmaf(c0.y, hv0, sre1); sim1 = fmaf(-s0.y, hv0, sim1);
        sre2 = fmaf(c0.z, hv0, sre2); sim2 = fmaf(-s0.z, hv0, sim2);
        sre3 = fmaf(c0.w, hv0, sre3); sim3 = fmaf(-s0.w, hv0, sim3);
    }

    float sre[4] = {sre0, sre1, sre2, sre3};
    float sim[4] = {sim0, sim1, sim2, sim3};
#pragma unroll
    for (int i = 0; i < 4; i++) {
        size_t idx = ((size_t)b * NK + k0 + i) * D_PET + d;
        float f = filt[idx];
        t_re[idx] = sre[i] * f;
        t_im[idx] = sim[i] * f;
    }
}

// ---------------------------------------------------------------------------
// Kernel 4: out[n,d] = sum_k e^{+i phi_nk} * t[batch[n],k,d]
// chunk = 4 atoms, grid = 16*32 = 512 blocks (all working), 256 threads.
// t read straight from L2 (coalesced, no barriers in k-loop); cos/sin staged
// once per chunk in 10 KB LDS and read as wave-uniform broadcasts.
// ---------------------------------------------------------------------------
#define OC 4        // atoms per chunk
#define OCHUNKS 32  // chunk stride
#define AP 5        // padded atom dim for cs rows
__global__ void out_kernel(const float* __restrict__ cos_t,
                           const float* __restrict__ sin_t,
                           const int* __restrict__ batch,
                           const float* __restrict__ t_re,
                           const float* __restrict__ t_im,
                           float* __restrict__ out, int interleaved) {
    int b  = blockIdx.x / OCHUNKS;
    int c0 = blockIdx.x % OCHUNKS;

    int lo = lower_bound_dev(batch, NB, b);
    int hi = lower_bound_dev(batch, NB, b + 1);
    int sz = hi - lo;

    int d  = threadIdx.x & (D_PET - 1);
    int ag = threadIdx.x >> 7;    // 0/1 -> atoms ag*2, ag*2+1

    __shared__ float2 cs[NK * AP];   // 10 KB

    const float* trg = t_re + (size_t)b * NK * D_PET + d;
    const float* tig = t_im + (size_t)b * NK * D_PET + d;

    for (int ch = c0; ch * OC < sz; ch += OCHUNKS) {
        int nb = lo + ch * OC;

        __syncthreads();   // protect cs from previous chunk's readers
        // stage cs[k][a] for the 4 atoms; coalesced reads, 2-way-bank writes
        for (int idx = threadIdx.x; idx < NK * OC; idx += 256) {
            int a = idx >> 8;            // 0..3
            int k = idx & (NK - 1);
            int n = nb + a;
            float c = 0.f, s = 0.f;
            if (n < hi) {
                c = cos_t[(size_t)n * NK + k];
                s = sin_t[(size_t)n * NK + k];
            }
            cs[k * AP + a] = make_float2(c, s);
        }
        __syncthreads();

        float ore0 = 0.f, oim0 = 0.f, ore1 = 0.f, oim1 = 0.f;
#pragma unroll 8
        for (int k = 0; k < NK; k++) {
            float tre = trg[(size_t)k * D_PET];
            float tim = tig[(size_t)k * D_PET];
            float2 p0 = cs[k * AP + ag * 2 + 0];
            float2 p1 = cs[k * AP + ag * 2 + 1];
            ore0 = fmaf(p0.x, tre, ore0); ore0 = fmaf(-p0.y, tim, ore0);
            oim0 = fmaf(p0.x, tim, oim0); oim0 = fmaf(p0.y, tre, oim0);
            ore1 = fmaf(p1.x, tre, ore1); ore1 = fmaf(-p1.y, tim, ore1);
            oim1 = fmaf(p1.x, tim, oim1); oim1 = fmaf(p1.y, tre, oim1);
        }

        int n0 = nb + ag * 2;
        if (interleaved) {
            float2* o2 = (float2*)out;
            if (n0 < hi)     o2[(size_t)n0 * D_PET + d]       = make_float2(ore0, oim0);
            if (n0 + 1 < hi) o2[(size_t)(n0 + 1) * D_PET + d] = make_float2(ore1, oim1);
        } else {
            if (n0 < hi)     out[(size_t)n0 * D_PET + d]       = ore0;
            if (n0 + 1 < hi) out[(size_t)(n0 + 1) * D_PET + d] = ore1;
        }
    }
}

// ---------------------------------------------------------------------------
extern "C" void kernel_launch(void* const* d_in, const int* in_sizes, int n_in,
                              void* d_out, int out_size, void* d_ws, size_t ws_size,
                              hipStream_t stream) {
    const float* kvec = (const float*)d_in[0];   // [16,256,3]
    const float* pos  = (const float*)d_in[1];   // [2048,3]
    const float* h    = (const float*)d_in[2];   // [2048,128]
    const float* W1   = (const float*)d_in[3];
    const float* b1   = (const float*)d_in[4];
    const float* W2   = (const float*)d_in[5];
    const float* b2   = (const float*)d_in[6];
    const float* W3   = (const float*)d_in[7];
    const float* b3   = (const float*)d_in[8];
    const int*   batch = (const int*)d_in[9];    // [2048]

    float* ws    = (float*)d_ws;
    float* filt  = ws;                                  // 16*256*128
    float* cos_t = filt  + (size_t)NBATCH * NK * D_PET; // 2048*256
    float* sin_t = cos_t + (size_t)NB * NK;
    float* t_re  = sin_t + (size_t)NB * NK;             // 16*256*128
    float* t_im  = t_re  + (size_t)NBATCH * NK * D_PET;

    int interleaved = (out_size == NB * D_PET * 2) ? 1 : 0;

    mlp_kernel<<<NBATCH * NK / MJ, 256, 0, stream>>>(kvec, W1, b1, W2, b2, W3, b3, filt);
    phase_kernel<<<NB, NK, 0, stream>>>(kvec, pos, batch, cos_t, sin_t);
    s_kernel<<<NBATCH * (NK / SKT), 256, 0, stream>>>(h, cos_t, sin_t, batch, filt, t_re, t_im);
    out_kernel<<<NBATCH * OCHUNKS, 256, 0, stream>>>(cos_t, sin_t, batch, t_re, t_im, (float*)d_out, interleaved);
}

// Round 4
// 180.665 us; speedup vs baseline: 1.2661x; 1.2661x over previous
//
#include <hip/hip_runtime.h>
#include <hip/hip_bf16.h>
#include <math.h>

#define D_PET 128
#define NK    256
#define NB    2048
#define NBATCH 16

__device__ __forceinline__ float silu(float x) {
    return x / (1.0f + expf(-x));
}

__device__ __forceinline__ int lower_bound_dev(const int* a, int n, int v) {
    int lo = 0, hi = n;
    while (lo < hi) {
        int m = (lo + hi) >> 1;
        if (a[m] < v) lo = m + 1; else hi = m;
    }
    return lo;
}

// ---------------------------------------------------------------------------
// Kernel 1: pc[n][k] = (cos, sin) of phase(n,k).  grid = NB blocks, NK thr.
// ---------------------------------------------------------------------------
__global__ __launch_bounds__(NK) void phase_kernel(
        const float* __restrict__ kvec, const float* __restrict__ pos,
        const int* __restrict__ batch, float2* __restrict__ pc) {
    int n = blockIdx.x;
    int k = threadIdx.x;
    int b = batch[n];
    float p0 = pos[n * 3 + 0], p1 = pos[n * 3 + 1], p2 = pos[n * 3 + 2];
    const float* kv = kvec + ((size_t)b * NK + k) * 3;
    float ph = fmaf(p0, kv[0], fmaf(p1, kv[1], p2 * kv[2]));
    float s, c;
    sincosf(ph, &s, &c);
    pc[(size_t)n * NK + k] = make_float2(c, s);
}

// ---------------------------------------------------------------------------
// Kernel 2 (fused MLP + segment-sum):
//   filt[b,k,d] computed in-register (8 k-vecs per block, same tiling as the
//   old mlp_kernel), then t2[b,k,d] = (sum_{n in b} e^{-i phi} h[n,d]) * filt
// grid = 16*32 = 512 blocks, 256 threads: d = tid&127, kg = tid>>7.
// Atom loop unrolled x4 -> 12 independent loads in flight per group.
// ---------------------------------------------------------------------------
#define SKT 8
__global__ __launch_bounds__(256) void s_fused_kernel(
        const float* __restrict__ h, const float2* __restrict__ pc,
        const int* __restrict__ batch, const float* __restrict__ kvec,
        const float* __restrict__ W1, const float* __restrict__ b1,
        const float* __restrict__ W2, const float* __restrict__ b2,
        const float* __restrict__ W3, const float* __restrict__ b3,
        float2* __restrict__ t2) {
    int b  = blockIdx.x >> 5;          // / 32
    int kt = blockIdx.x & 31;
    int d  = threadIdx.x & (D_PET - 1);
    int kg = threadIdx.x >> 7;         // 0/1
    int bk0 = b * NK + kt * SKT;       // first flat k-vector index of block
    int k0  = kt * SKT + kg * 4;       // this thread's first k

    __shared__ float kv_s[SKT * 3];
    __shared__ float x_lds[D_PET * SKT];

    if (threadIdx.x < SKT * 3) kv_s[threadIdx.x] = kvec[bk0 * 3 + threadIdx.x];
    __syncthreads();

    // ---- layer 1: 3 -> 128, silu ----
    float w10 = W1[d], w11 = W1[D_PET + d], w12 = W1[2 * D_PET + d];
    float bb1 = b1[d];
    float4 x1;
    {
        float* xp = (float*)&x1;
#pragma unroll
        for (int i = 0; i < 4; i++) {
            int j = kg * 4 + i;
            float a = bb1;
            a = fmaf(kv_s[j * 3 + 0], w10, a);
            a = fmaf(kv_s[j * 3 + 1], w11, a);
            a = fmaf(kv_s[j * 3 + 2], w12, a);
            xp[i] = silu(a);
        }
    }
    *(float4*)&x_lds[(d << 3) + (kg << 2)] = x1;
    __syncthreads();

    // ---- layer 2: 128 -> 128, silu ----
    float a0 = b2[d], a1 = a0, a2 = a0, a3 = a0;
#pragma unroll 8
    for (int e = 0; e < D_PET; e++) {
        float w = W2[e * D_PET + d];
        float4 xv = *(const float4*)&x_lds[(e << 3) + (kg << 2)];
        a0 = fmaf(xv.x, w, a0);
        a1 = fmaf(xv.y, w, a1);
        a2 = fmaf(xv.z, w, a2);
        a3 = fmaf(xv.w, w, a3);
    }
    float4 x2 = make_float4(silu(a0), silu(a1), silu(a2), silu(a3));
    __syncthreads();
    *(float4*)&x_lds[(d << 3) + (kg << 2)] = x2;
    __syncthreads();

    // ---- layer 3: 128 -> 128 -> filt in registers ----
    float f0 = b3[d], f1 = f0, f2 = f0, f3 = f0;
#pragma unroll 8
    for (int e = 0; e < D_PET; e++) {
        float w = W3[e * D_PET + d];
        float4 xv = *(const float4*)&x_lds[(e << 3) + (kg << 2)];
        f0 = fmaf(xv.x, w, f0);
        f1 = fmaf(xv.y, w, f1);
        f2 = fmaf(xv.z, w, f2);
        f3 = fmaf(xv.w, w, f3);
    }

    // ---- segment sum over atoms of this batch ----
    int lo = lower_bound_dev(batch, NB, b);
    int hi = lower_bound_dev(batch, NB, b + 1);

    float sre0 = 0.f, sre1 = 0.f, sre2 = 0.f, sre3 = 0.f;
    float sim0 = 0.f, sim1 = 0.f, sim2 = 0.f, sim3 = 0.f;

    int n = lo;
    for (; n + 3 < hi; n += 4) {
#pragma unroll
        for (int u = 0; u < 4; u++) {
            int nn = n + u;
            float hv = h[(size_t)nn * D_PET + d];
            const float4* pp = (const float4*)(pc + (size_t)nn * NK + k0);
            float4 q0 = pp[0];   // c0,s0,c1,s1
            float4 q1 = pp[1];   // c2,s2,c3,s3
            sre0 = fmaf(q0.x, hv, sre0); sim0 = fmaf(-q0.y, hv, sim0);
            sre1 = fmaf(q0.z, hv, sre1); sim1 = fmaf(-q0.w, hv, sim1);
            sre2 = fmaf(q1.x, hv, sre2); sim2 = fmaf(-q1.y, hv, sim2);
            sre3 = fmaf(q1.z, hv, sre3); sim3 = fmaf(-q1.w, hv, sim3);
        }
    }
    for (; n < hi; n++) {
        float hv = h[(size_t)n * D_PET + d];
        const float4* pp = (const float4*)(pc + (size_t)n * NK + k0);
        float4 q0 = pp[0];
        float4 q1 = pp[1];
        sre0 = fmaf(q0.x, hv, sre0); sim0 = fmaf(-q0.y, hv, sim0);
        sre1 = fmaf(q0.z, hv, sre1); sim1 = fmaf(-q0.w, hv, sim1);
        sre2 = fmaf(q1.x, hv, sre2); sim2 = fmaf(-q1.y, hv, sim2);
        sre3 = fmaf(q1.z, hv, sre3); sim3 = fmaf(-q1.w, hv, sim3);
    }

    float fr[4]  = {f0, f1, f2, f3};
    float srr[4] = {sre0, sre1, sre2, sre3};
    float sii[4] = {sim0, sim1, sim2, sim3};
#pragma unroll
    for (int i = 0; i < 4; i++) {
        size_t idx = ((size_t)b * NK + k0 + i) * D_PET + d;
        t2[idx] = make_float2(srr[i] * fr[i], sii[i] * fr[i]);
    }
}

// ---------------------------------------------------------------------------
// Kernel 3: out[n,d] = sum_k e^{+i phi_nk} * t2[batch[n],k,d]
// 4 atoms/chunk, 512 blocks all working, 256 threads (d = tid&127, ag=tid>>7
// -> 2 atoms each). t2 double-buffered through LDS in 16-k tiles with
// register prefetch; cos/sin in LDS, read as wave-uniform b128 broadcasts.
// LDS = 2*16KB + 12KB = 44 KB -> 3 blocks/CU.
// ---------------------------------------------------------------------------
#define OC    4     // atoms per chunk
#define OCH   32    // chunks (blocks) per batch
#define OKT   16    // k per tile
#define NTILE (NK / OKT)   // 16
#define AP    6     // padded atom dim for cs rows (even -> 16B-aligned f4)
__global__ __launch_bounds__(256) void out_kernel(
        const float2* __restrict__ pc, const int* __restrict__ batch,
        const float2* __restrict__ t2, float* __restrict__ out,
        int interleaved) {
    int b  = blockIdx.x >> 5;
    int c0 = blockIdx.x & 31;
    int d  = threadIdx.x & (D_PET - 1);
    int ag = threadIdx.x >> 7;   // 0/1 -> atoms ag*2, ag*2+1

    int lo = lower_bound_dev(batch, NB, b);
    int hi = lower_bound_dev(batch, NB, b + 1);
    int sz = hi - lo;

    __shared__ float2 cs[NK * AP];                 // 12 KB
    __shared__ float  tbuf[2][OKT * D_PET * 2];    // 2 x 16 KB

    const float4* tg4 = (const float4*)(t2 + (size_t)b * NK * D_PET);
    // one tile = OKT*D_PET float2 = 1024 float4

    for (int ch = c0; ch * OC < sz; ch += OCH) {
        int nb = lo + ch * OC;
        __syncthreads();   // protect cs/tbuf from previous chunk's readers

        // stage cs[k][a] for the 4 atoms (coalesced b64 reads)
        for (int idx = threadIdx.x; idx < NK * OC; idx += 256) {
            int k = idx & (NK - 1);
            int a = idx >> 8;
            int n = nb + a;
            float2 v = make_float2(0.f, 0.f);
            if (n < hi) v = pc[(size_t)n * NK + k];
            cs[k * AP + a] = v;
        }

        // stage tile 0 into buffer 0
        float4 r[4];
#pragma unroll
        for (int j = 0; j < 4; j++) r[j] = tg4[j * 256 + threadIdx.x];
#pragma unroll
        for (int j = 0; j < 4; j++)
            *(float4*)&tbuf[0][(j * 256 + threadIdx.x) * 4] = r[j];
        __syncthreads();

        float ore0 = 0.f, oim0 = 0.f, ore1 = 0.f, oim1 = 0.f;

        for (int kt = 0; kt < NTILE; kt++) {
            int cur = kt & 1;
            // prefetch next tile into registers (latency hidden by compute)
            if (kt + 1 < NTILE) {
#pragma unroll
                for (int j = 0; j < 4; j++)
                    r[j] = tg4[(size_t)(kt + 1) * 1024 + j * 256 + threadIdx.x];
            }
            const float2* tb = (const float2*)tbuf[cur];
#pragma unroll
            for (int kk = 0; kk < OKT; kk++) {
                float2 tv = tb[kk * D_PET + d];            // ds_read_b64
                int k = kt * OKT + kk;
                float4 p = *(const float4*)&cs[k * AP + ag * 2]; // broadcast b128
                ore0 = fmaf(p.x, tv.x, ore0); ore0 = fmaf(-p.y, tv.y, ore0);
                oim0 = fmaf(p.x, tv.y, oim0); oim0 = fmaf(p.y, tv.x, oim0);
                ore1 = fmaf(p.z, tv.x, ore1); ore1 = fmaf(-p.w, tv.y, ore1);
                oim1 = fmaf(p.z, tv.y, oim1); oim1 = fmaf(p.w, tv.x, oim1);
            }
            __syncthreads();   // everyone done reading tbuf[1-cur] (2 tiles ago)
            if (kt + 1 < NTILE) {
#pragma unroll
                for (int j = 0; j < 4; j++)
                    *(float4*)&tbuf[1 - cur][(j * 256 + threadIdx.x) * 4] = r[j];
            }
            __syncthreads();   // next buffer ready
        }

        int n0 = nb + ag * 2;
        if (interleaved) {
            float2* o2 = (float2*)out;
            if (n0 < hi)     o2[(size_t)n0 * D_PET + d]       = make_float2(ore0, oim0);
            if (n0 + 1 < hi) o2[(size_t)(n0 + 1) * D_PET + d] = make_float2(ore1, oim1);
        } else {
            if (n0 < hi)     out[(size_t)n0 * D_PET + d]       = ore0;
            if (n0 + 1 < hi) out[(size_t)(n0 + 1) * D_PET + d] = ore1;
        }
    }
}

// ---------------------------------------------------------------------------
extern "C" void kernel_launch(void* const* d_in, const int* in_sizes, int n_in,
                              void* d_out, int out_size, void* d_ws, size_t ws_size,
                              hipStream_t stream) {
    const float* kvec = (const float*)d_in[0];   // [16,256,3]
    const float* pos  = (const float*)d_in[1];   // [2048,3]
    const float* h    = (const float*)d_in[2];   // [2048,128]
    const float* W1   = (const float*)d_in[3];
    const float* b1   = (const float*)d_in[4];
    const float* W2   = (const float*)d_in[5];
    const float* b2   = (const float*)d_in[6];
    const float* W3   = (const float*)d_in[7];
    const float* b3   = (const float*)d_in[8];
    const int*   batch = (const int*)d_in[9];    // [2048]

    float2* pc = (float2*)d_ws;                              // [NB][NK]    4 MB
    float2* t2 = pc + (size_t)NB * NK;                       // [B][NK][D]  4 MB

    int interleaved = (out_size == NB * D_PET * 2) ? 1 : 0;

    phase_kernel<<<NB, NK, 0, stream>>>(kvec, pos, batch, pc);
    s_fused_kernel<<<NBATCH * 32, 256, 0, stream>>>(h, pc, batch, kvec,
                                                    W1, b1, W2, b2, W3, b3, t2);
    out_kernel<<<NBATCH * OCH, 256, 0, stream>>>(pc, batch, t2,
                                                 (float*)d_out, interleaved);
}